// Round 17
// baseline (287.960 us; speedup 1.0000x reference)
//
#include <hip/hip_runtime.h>
#include <hip/hip_bf16.h>
#include <math.h>

#define DEV __device__ __forceinline__

static constexpr int LL = 4096;   // H*W
static constexpr int DD = 128;    // hidden
static constexpr int SEG = 128;   // segments per scan (32 positions each)
static constexpr float LOG2E = 1.4426950408889634f;
static constexpr float LN2 = 0.6931471805599453f;

typedef short bf16x8 __attribute__((ext_vector_type(8)));
typedef float f32x4 __attribute__((ext_vector_type(4)));

DEV float silu_(float x) { return x / (1.f + __expf(-x)); }
// A&S 7.1.26 erf approximation, |err| <= 1.5e-7
DEV float erf_(float x) {
  const float ax = fabsf(x);
  const float t = 1.f / fmaf(0.3275911f, ax, 1.f);
  float p = fmaf(1.061405429f, t, -1.453152027f);
  p = fmaf(p, t, 1.421413741f);
  p = fmaf(p, t, -0.284496736f);
  p = fmaf(p, t, 0.254829592f);
  p = p * t;
  const float r = 1.f - p * __expf(-ax * ax);
  return x < 0.f ? -r : r;
}
DEV float gelu_(float x) { return 0.5f * x * (1.f + erf_(x * 0.7071067811865475f)); }
DEV float sp_(float x) {
  const float t = __builtin_amdgcn_exp2f(-fabsf(x) * LOG2E);
  return fmaxf(x, 0.f) + LN2 * __builtin_amdgcn_logf(1.f + t);
}

template <int CTRL>
DEV float dpp_add_(float x) {
  int y = __builtin_amdgcn_update_dpp(0, __float_as_int(x), CTRL, 0xF, 0xF, true);
  return x + __int_as_float(y);
}

DEV short f2bf(float f) {
  unsigned u = __float_as_uint(f);
  u += 0x7FFF + ((u >> 16) & 1);
  return (short)(u >> 16);
}
DEV bf16x8 cvt8(float4 a, float4 b) {
  bf16x8 r;
  r[0] = f2bf(a.x); r[1] = f2bf(a.y); r[2] = f2bf(a.z); r[3] = f2bf(a.w);
  r[4] = f2bf(b.x); r[5] = f2bf(b.y); r[6] = f2bf(b.z); r[7] = f2bf(b.w);
  return r;
}

// 64-position tiles (used by x_proj): tile s of direction k
DEV void seg_base_step(int k, int s, int& base, int& step) {
  if (k == 0)      { base = s * 64;        step = 1;   }
  else if (k == 1) { base = s;             step = 64;  }
  else if (k == 2) { base = 4095 - s * 64; step = -1;  }
  else             { base = 4095 - s;      step = -64; }
}

// ---------------- K1: in_proj via bf16 MFMA; coalesced store via LDS ------
__global__ __launch_bounds__(256) void k_inproj(
    const float* __restrict__ sar, const float* __restrict__ opt,
    const float* __restrict__ in_w, float* __restrict__ xz) {
  const int lt = blockIdx.x, ct = blockIdx.y, mb = blockIdx.z;
  const int m = mb >> 2;
  const float* __restrict__ x = (m == 0 ? opt : sar) + (size_t)(mb & 3) * (LL * DD);
  const float* __restrict__ W = in_w + (size_t)m * 256 * DD + (size_t)ct * 64 * DD;
  __shared__ float sOut[64][65];
  const int tid = threadIdx.x;
  const int lane = tid & 63, wv = tid >> 6;
  const int lr = lane & 15, kg = (lane >> 4) * 8;
  const int lrow = lt * 64 + wv * 16 + lr;            // x row / output col
  f32x4 acc[4] = {};
#pragma unroll
  for (int ks = 0; ks < 4; ++ks) {
    const int d0 = ks * 32 + kg;
    const float* __restrict__ xp = x + (size_t)lrow * DD + d0;
    const bf16x8 bfr = cvt8(*(const float4*)xp, *(const float4*)(xp + 4));
#pragma unroll
    for (int ctl = 0; ctl < 4; ++ctl) {
      const float* __restrict__ wp = W + (size_t)(ctl * 16 + lr) * DD + d0;
      const bf16x8 afr = cvt8(*(const float4*)wp, *(const float4*)(wp + 4));
      acc[ctl] = __builtin_amdgcn_mfma_f32_16x16x32_bf16(afr, bfr, acc[ctl], 0, 0, 0);
    }
  }
  // stage [c][l] tile in LDS, write rows coalesced
  const int lloc = wv * 16 + lr;
  const int cr0 = (lane >> 4) * 4;
#pragma unroll
  for (int ctl = 0; ctl < 4; ++ctl)
#pragma unroll
    for (int r = 0; r < 4; ++r)
      sOut[cr0 + ctl * 16 + r][lloc] = acc[ctl][r];
  __syncthreads();
  float* __restrict__ dst = xz + (size_t)mb * 256 * LL + lt * 64;
#pragma unroll
  for (int t = 0; t < 4; ++t) {
    const int idx = tid + t * 256;
    const int row = idx >> 4, c4 = (idx & 15) << 2;
    *(float4*)&dst[(size_t)(ct * 64 + row) * LL + c4] = *(const float4*)&sOut[row][c4];
  }
}

// ---------------- K2: depthwise 3x3 SAME conv + bias + SiLU ---------------
__global__ __launch_bounds__(256) void k_conv(
    const float* __restrict__ xz, const float* __restrict__ conv_w,
    const float* __restrict__ conv_b, float* __restrict__ xc) {
  const int ht = blockIdx.x, dg = blockIdx.y, mb = blockIdx.z;
  const int m = mb >> 2;
  __shared__ float sIn[8][18][66];
  __shared__ float sOut[1024][8];
  const float* __restrict__ src = xz + ((size_t)mb * 256 + dg * 8) * LL;
  const int tid = threadIdx.x;
  for (int idx = tid; idx < 8 * 18 * 66; idx += 256) {
    const int dd = idx / (18 * 66);
    const int rem = idx - dd * (18 * 66);
    const int hh = rem / 66, ww = rem - hh * 66;
    const int h = ht * 16 + hh - 1, w = ww - 1;
    float v = 0.f;
    if (h >= 0 && h < 64 && w >= 0 && w < 64) v = src[(size_t)dd * LL + h * 64 + w];
    sIn[dd][hh][ww] = v;
  }
  __syncthreads();
  const int dd = tid & 7, wv = tid >> 3;
  const int dch = dg * 8 + dd;
  float wk[9];
#pragma unroll
  for (int t = 0; t < 9; ++t) wk[t] = conv_w[((size_t)m * DD + dch) * 9 + t];
  const float bias = conv_b[m * DD + dch];
  for (int hh = 0; hh < 16; ++hh) {
#pragma unroll
    for (int wh = 0; wh < 2; ++wh) {
      const int w = wv + wh * 32;
      float s = bias;
#pragma unroll
      for (int kh = 0; kh < 3; ++kh)
#pragma unroll
        for (int kw = 0; kw < 3; ++kw)
          s = fmaf(sIn[dd][hh + kh][w + kw], wk[kh * 3 + kw], s);
      sOut[hh * 64 + w][dd] = silu_(s);
    }
  }
  __syncthreads();
  float* __restrict__ dst = xc + (size_t)mb * LL * DD + dg * 8;
#pragma unroll
  for (int r = 0; r < 4; ++r) {
    const int pos = tid + r * 256;
    const int l = ht * 1024 + pos;
    *(float4*)&dst[(size_t)l * DD + 0] = *(const float4*)&sOut[pos][0];
    *(float4*)&dst[(size_t)l * DD + 4] = *(const float4*)&sOut[pos][4];
  }
}

// ---------------- K3: x_proj (paired dirs k, k+2) -> xdbl[mbk][l][24] -----
__global__ __launch_bounds__(256) void k_xproj(
    const float* __restrict__ xc, const float* __restrict__ xproj_w,
    float* __restrict__ xdbl) {
  const int lt = blockIdx.x, p = blockIdx.y, mb = blockIdx.z;
  const int m = mb >> 2;
  const int mbkA = mb * 4 + p, mbkB = mb * 4 + p + 2;
  __shared__ float sX[64][132];
  __shared__ float sWA[24][132];
  __shared__ float sWB[24][132];
  const int tid = threadIdx.x;
  const float* __restrict__ src = xc + (size_t)mb * LL * DD;
  int base, step;
  seg_base_step(p, lt, base, step);
  for (int idx = tid; idx < 64 * 32; idx += 256) {
    const int l = idx >> 5, d4 = (idx & 31) << 2;
    *(float4*)&sX[l][d4] = *(const float4*)&src[(size_t)(base + l * step) * DD + d4];
  }
  const float* __restrict__ WsA = xproj_w + ((size_t)m * 4 + p) * 24 * DD;
  const float* __restrict__ WsB = xproj_w + ((size_t)m * 4 + p + 2) * 24 * DD;
  for (int idx = tid; idx < 24 * 32; idx += 256) {
    const int r = idx >> 5, d4 = (idx & 31) << 2;
    *(float4*)&sWA[r][d4] = *(const float4*)&WsA[(size_t)r * DD + d4];
    *(float4*)&sWB[r][d4] = *(const float4*)&WsB[(size_t)r * DD + d4];
  }
  __syncthreads();
  const int l = tid >> 2, cg = tid & 3;
  float acc[6] = {}, acc2[6] = {};
#pragma unroll 8
  for (int d = 0; d < 128; d += 4) {
    const float4 xv = *(const float4*)&sX[l][d];
#pragma unroll
    for (int j = 0; j < 6; ++j) {
      const float4 wa = *(const float4*)&sWA[cg * 6 + j][d];
      const float4 wb = *(const float4*)&sWB[cg * 6 + j][d];
      acc[j] += xv.x * wa.x + xv.y * wa.y + xv.z * wa.z + xv.w * wa.w;
      acc2[j] += xv.x * wb.x + xv.y * wb.y + xv.z * wb.z + xv.w * wb.w;
    }
  }
  const int rowA = lt * 64 + l;
  float* __restrict__ dstA = xdbl + ((size_t)mbkA * LL + rowA) * 24 + cg * 6;
  float* __restrict__ dstB = xdbl + ((size_t)mbkB * LL + (4095 - rowA)) * 24 + cg * 6;
#pragma unroll
  for (int j = 0; j < 6; ++j) { dstA[j] = acc[j]; dstB[j] = acc2[j]; }
}

// ============== dual-chain segmented selective scan (SEGL=32) =============
// x strip held in 32 REGISTERS per thread (no LDS, no barrier); t24 rows
// read from global at wave-uniform addresses (scalar/broadcast, L1-hot).

DEV void load_aln2(const float* __restrict__ Alogs, int m, int k, int d,
                   float* __restrict__ aln2, bool& fastp) {
  const float4 a0 = *(const float4*)&Alogs[((size_t)m * 512 + k * DD + d) * 8];
  const float4 a1 = *(const float4*)&Alogs[((size_t)m * 512 + k * DD + d) * 8 + 4];
  aln2[0] = -__expf(a0.x) * LOG2E; aln2[1] = -__expf(a0.y) * LOG2E;
  aln2[2] = -__expf(a0.z) * LOG2E; aln2[3] = -__expf(a0.w) * LOG2E;
  aln2[4] = -__expf(a1.x) * LOG2E; aln2[5] = -__expf(a1.y) * LOG2E;
  aln2[6] = -__expf(a1.z) * LOG2E; aln2[7] = -__expf(a1.w) * LOG2E;
  fastp = true;
#pragma unroll
  for (int n = 1; n < 8; ++n)
    fastp = fastp && (fabsf(aln2[n] - (float)(n + 1) * aln2[0]) <=
                      1e-4f * fabsf(aln2[n]) + 1e-12f);
}

DEV void load_w8(const float* __restrict__ dt_w, int mbk, int d,
                 float* __restrict__ wreg) {
  const float4 w0 = *(const float4*)&dt_w[((size_t)mbk * DD + d) * 8];
  const float4 w1 = *(const float4*)&dt_w[((size_t)mbk * DD + d) * 8 + 4];
  wreg[0] = w0.x; wreg[1] = w0.y; wreg[2] = w0.z; wreg[3] = w0.w;
  wreg[4] = w1.x; wreg[5] = w1.y; wreg[6] = w1.z; wreg[7] = w1.w;
}

template <bool FAST>
DEV void qpow_(float dt, const float* __restrict__ aln2, float* __restrict__ q) {
  if constexpr (FAST) {
    q[0] = __builtin_amdgcn_exp2f(dt * aln2[0]);
    q[1] = q[0] * q[0]; q[2] = q[1] * q[0]; q[3] = q[1] * q[1];
    q[4] = q[3] * q[0]; q[5] = q[3] * q[1]; q[6] = q[3] * q[2]; q[7] = q[3] * q[3];
  } else {
#pragma unroll
    for (int n = 0; n < 8; ++n) q[n] = __builtin_amdgcn_exp2f(dt * aln2[n]);
  }
}

// t24 = uniform pointer to this step's 24-float row {dts[8], B[8], C[8]}
DEV float dt_of_(const float* __restrict__ t24,
                 const float* __restrict__ w, float bw) {
  const float4 t0 = *(const float4*)&t24[0];
  const float4 t1 = *(const float4*)&t24[4];
  float s = bw;
  s = fmaf(t0.x, w[0], s); s = fmaf(t0.y, w[1], s);
  s = fmaf(t0.z, w[2], s); s = fmaf(t0.w, w[3], s);
  s = fmaf(t1.x, w[4], s); s = fmaf(t1.y, w[5], s);
  s = fmaf(t1.z, w[6], s); s = fmaf(t1.w, w[7], s);
  return sp_(s);
}

template <bool FAST>
DEV void hstep_(const float* __restrict__ t24, float dt, float x,
                const float* __restrict__ aln2, float* __restrict__ h) {
  const float u = dt * x;
  float q[8];
  qpow_<FAST>(dt, aln2, q);
  const float4 b0 = *(const float4*)&t24[8];
  const float4 b1 = *(const float4*)&t24[12];
  h[0] = fmaf(h[0], q[0], u * b0.x);
  h[1] = fmaf(h[1], q[1], u * b0.y);
  h[2] = fmaf(h[2], q[2], u * b0.z);
  h[3] = fmaf(h[3], q[3], u * b0.w);
  h[4] = fmaf(h[4], q[4], u * b1.x);
  h[5] = fmaf(h[5], q[5], u * b1.y);
  h[6] = fmaf(h[6], q[6], u * b1.z);
  h[7] = fmaf(h[7], q[7], u * b1.w);
}

template <bool FAST>
DEV float ystep_(const float* __restrict__ t24, float dt, float x,
                 const float* __restrict__ aln2, float dsv,
                 float* __restrict__ h) {
  const float u = dt * x;
  float q[8];
  qpow_<FAST>(dt, aln2, q);
  const float4 b0 = *(const float4*)&t24[8];
  const float4 b1 = *(const float4*)&t24[12];
  const float4 c0 = *(const float4*)&t24[16];
  const float4 c1 = *(const float4*)&t24[20];
  float y = dsv * x;
  h[0] = fmaf(h[0], q[0], u * b0.x); y = fmaf(h[0], c0.x, y);
  h[1] = fmaf(h[1], q[1], u * b0.y); y = fmaf(h[1], c0.y, y);
  h[2] = fmaf(h[2], q[2], u * b0.z); y = fmaf(h[2], c0.z, y);
  h[3] = fmaf(h[3], q[3], u * b0.w); y = fmaf(h[3], c0.w, y);
  h[4] = fmaf(h[4], q[4], u * b1.x); y = fmaf(h[4], c1.x, y);
  h[5] = fmaf(h[5], q[5], u * b1.y); y = fmaf(h[5], c1.y, y);
  h[6] = fmaf(h[6], q[6], u * b1.z); y = fmaf(h[6], c1.z, y);
  h[7] = fmaf(h[7], q[7], u * b1.w); y = fmaf(h[7], c1.w, y);
  return y;
}

// ---- pass 1: dual-chain local scan (h0=0) -> h_end, P --------------------
template <bool FAST>
DEV void loop1d_(const float* __restrict__ tA, const float* __restrict__ tB,
                 const float* __restrict__ xr,
                 const float* __restrict__ aln2A, const float* __restrict__ aln2B,
                 const float* __restrict__ wA, const float* __restrict__ wB,
                 float bwA, float bwB, float* __restrict__ hA,
                 float* __restrict__ hB, float& dtsA, float& dtsB) {
#pragma unroll
  for (int j = 0; j < 32; ++j) {
    const float dtA = dt_of_(tA + j * 24, wA, bwA);
    const float dtB = dt_of_(tB + j * 24, wB, bwB);
    dtsA += dtA; dtsB += dtB;
    hstep_<FAST>(tA + j * 24, dtA, xr[j], aln2A, hA);
    hstep_<FAST>(tB + j * 24, dtB, xr[31 - j], aln2B, hB);
  }
}

__global__ __launch_bounds__(128) void k_scan1(
    const float* __restrict__ xc, const float* __restrict__ xdbl,
    const float* __restrict__ dt_w, const float* __restrict__ dt_b,
    const float* __restrict__ Alogs, float* __restrict__ hend,
    float* __restrict__ Pseg) {
  const int s = blockIdx.x, p = blockIdx.y, mb = blockIdx.z;
  const int m = mb >> 2;
  const int kA = p, kB = p + 2;
  const int sA = s, sB = 127 - s;
  const int mbkA = mb * 4 + kA, mbkB = mb * 4 + kB;
  const int d = threadIdx.x;

  const float* __restrict__ tA = xdbl + ((size_t)mbkA * LL + sA * 32) * 24;
  const float* __restrict__ tB = xdbl + ((size_t)mbkB * LL + sB * 32) * 24;

  const int base0 = (p == 0) ? s * 32 : ((s & 1) * 32) * 64 + (s >> 1);
  const int stepPos = (p == 0) ? 1 : 64;
  const float* __restrict__ xsrc = xc + (size_t)mb * LL * DD + (size_t)base0 * DD + d;
  const ptrdiff_t xst = (ptrdiff_t)stepPos * DD;
  float xr[32];
#pragma unroll
  for (int j = 0; j < 32; ++j) xr[j] = xsrc[(ptrdiff_t)j * xst];

  float aln2A[8], aln2B[8]; bool fA, fB;
  load_aln2(Alogs, m, kA, d, aln2A, fA);
  load_aln2(Alogs, m, kB, d, aln2B, fB);
  float wA[8], wB[8];
  load_w8(dt_w, mbkA, d, wA);
  load_w8(dt_w, mbkB, d, wB);
  const float bwA = dt_b[(size_t)mbkA * DD + d];
  const float bwB = dt_b[(size_t)mbkB * DD + d];

  float hA[8] = {0, 0, 0, 0, 0, 0, 0, 0};
  float hB[8] = {0, 0, 0, 0, 0, 0, 0, 0};
  float dtsA = 0.f, dtsB = 0.f;
  if (fA && fB)
    loop1d_<true>(tA, tB, xr, aln2A, aln2B, wA, wB, bwA, bwB, hA, hB, dtsA, dtsB);
  else
    loop1d_<false>(tA, tB, xr, aln2A, aln2B, wA, wB, bwA, bwB, hA, hB, dtsA, dtsB);

  {
    float* __restrict__ he = hend + (((size_t)mbkA * SEG + sA) << 10) + d * 8;
    float* __restrict__ pe = Pseg + (((size_t)mbkA * SEG + sA) << 10) + d * 8;
    *(float4*)&he[0] = make_float4(hA[0], hA[1], hA[2], hA[3]);
    *(float4*)&he[4] = make_float4(hA[4], hA[5], hA[6], hA[7]);
    *(float4*)&pe[0] = make_float4(
        __builtin_amdgcn_exp2f(aln2A[0] * dtsA), __builtin_amdgcn_exp2f(aln2A[1] * dtsA),
        __builtin_amdgcn_exp2f(aln2A[2] * dtsA), __builtin_amdgcn_exp2f(aln2A[3] * dtsA));
    *(float4*)&pe[4] = make_float4(
        __builtin_amdgcn_exp2f(aln2A[4] * dtsA), __builtin_amdgcn_exp2f(aln2A[5] * dtsA),
        __builtin_amdgcn_exp2f(aln2A[6] * dtsA), __builtin_amdgcn_exp2f(aln2A[7] * dtsA));
  }
  {
    float* __restrict__ he = hend + (((size_t)mbkB * SEG + sB) << 10) + d * 8;
    float* __restrict__ pe = Pseg + (((size_t)mbkB * SEG + sB) << 10) + d * 8;
    *(float4*)&he[0] = make_float4(hB[0], hB[1], hB[2], hB[3]);
    *(float4*)&he[4] = make_float4(hB[4], hB[5], hB[6], hB[7]);
    *(float4*)&pe[0] = make_float4(
        __builtin_amdgcn_exp2f(aln2B[0] * dtsB), __builtin_amdgcn_exp2f(aln2B[1] * dtsB),
        __builtin_amdgcn_exp2f(aln2B[2] * dtsB), __builtin_amdgcn_exp2f(aln2B[3] * dtsB));
    *(float4*)&pe[4] = make_float4(
        __builtin_amdgcn_exp2f(aln2B[4] * dtsB), __builtin_amdgcn_exp2f(aln2B[5] * dtsB),
        __builtin_amdgcn_exp2f(aln2B[6] * dtsB), __builtin_amdgcn_exp2f(aln2B[7] * dtsB));
  }
}

// ---- pass 2: sequential combine across 128 segments -> h_in --------------
__global__ __launch_bounds__(256) void k_scan2(
    const float* __restrict__ hend, const float* __restrict__ Pseg,
    float* __restrict__ hin) {
  const int gid = blockIdx.x * 256 + threadIdx.x;   // 32768
  const int mbk = gid >> 10, dn = gid & 1023;
  const float* __restrict__ P = Pseg + ((size_t)mbk * SEG << 10) + dn;
  const float* __restrict__ E = hend + ((size_t)mbk * SEG << 10) + dn;
  float* __restrict__ O = hin + ((size_t)mbk * SEG << 10) + dn;
  float h = 0.f;
  for (int c0 = 0; c0 < SEG; c0 += 16) {
    float pv[16], ev[16];
#pragma unroll
    for (int t = 0; t < 16; ++t) {
      pv[t] = P[(size_t)(c0 + t) << 10];
      ev[t] = E[(size_t)(c0 + t) << 10];
    }
#pragma unroll
    for (int t = 0; t < 16; ++t) {
      O[(size_t)(c0 + t) << 10] = h;
      h = fmaf(pv[t], h, ev[t]);
    }
  }
}

// ---- pass 3: dual-chain seeded scan; chains combined in registers --------
template <bool FAST>
DEV void chainA_(const float* __restrict__ t24, const float* __restrict__ xr,
                 const float* __restrict__ aln2, const float* __restrict__ w,
                 float bw, float dsv, float* __restrict__ h,
                 float* __restrict__ va) {
#pragma unroll
  for (int j = 0; j < 32; ++j) {
    const float dt = dt_of_(t24 + j * 24, w, bw);
    va[j] = ystep_<FAST>(t24 + j * 24, dt, xr[j], aln2, dsv, h);
  }
}

template <bool FAST>
DEV void chainB_(const float* __restrict__ t24, const float* __restrict__ xr,
                 const float* __restrict__ aln2, const float* __restrict__ w,
                 float bw, float dsv, float* __restrict__ h,
                 const float* __restrict__ va, float* __restrict__ yd,
                 ptrdiff_t sstep) {
#pragma unroll
  for (int j = 0; j < 32; ++j) {
    const int phys = 31 - j;
    const float dt = dt_of_(t24 + j * 24, w, bw);
    const float v = ystep_<FAST>(t24 + j * 24, dt, xr[phys], aln2, dsv, h);
    yd[(ptrdiff_t)phys * sstep] = v + va[phys];
  }
}

__global__ __launch_bounds__(128) void k_scan3(
    const float* __restrict__ xc, const float* __restrict__ xdbl,
    const float* __restrict__ dt_w, const float* __restrict__ dt_b,
    const float* __restrict__ Alogs, const float* __restrict__ Ds,
    const float* __restrict__ hin, float* __restrict__ yrow,
    float* __restrict__ ycol) {
  const int s = blockIdx.x, p = blockIdx.y, mb = blockIdx.z;
  const int m = mb >> 2;
  const int kA = p, kB = p + 2;
  const int sA = s, sB = 127 - s;
  const int mbkA = mb * 4 + kA, mbkB = mb * 4 + kB;
  const int d = threadIdx.x;

  const float* __restrict__ tA = xdbl + ((size_t)mbkA * LL + sA * 32) * 24;
  const float* __restrict__ tB = xdbl + ((size_t)mbkB * LL + sB * 32) * 24;

  const int base0 = (p == 0) ? s * 32 : ((s & 1) * 32) * 64 + (s >> 1);
  const int stepPos = (p == 0) ? 1 : 64;
  const size_t off0 = (size_t)mb * LL * DD + (size_t)base0 * DD + d;
  const float* __restrict__ xsrc = xc + off0;
  const ptrdiff_t xst = (ptrdiff_t)stepPos * DD;
  float xr[32];
#pragma unroll
  for (int j = 0; j < 32; ++j) xr[j] = xsrc[(ptrdiff_t)j * xst];

  float aln2A[8], aln2B[8]; bool fA, fB;
  load_aln2(Alogs, m, kA, d, aln2A, fA);
  load_aln2(Alogs, m, kB, d, aln2B, fB);
  float wA[8], wB[8];
  load_w8(dt_w, mbkA, d, wA);
  load_w8(dt_w, mbkB, d, wB);
  const float bwA = dt_b[(size_t)mbkA * DD + d];
  const float bwB = dt_b[(size_t)mbkB * DD + d];
  const float dsvA = Ds[(size_t)m * 512 + kA * DD + d];
  const float dsvB = Ds[(size_t)m * 512 + kB * DD + d];

  float hA[8], hB[8];
  {
    const float* hp = hin + (((size_t)mbkA * SEG + sA) << 10) + d * 8;
    const float4 h0 = *(const float4*)&hp[0];
    const float4 h1 = *(const float4*)&hp[4];
    hA[0] = h0.x; hA[1] = h0.y; hA[2] = h0.z; hA[3] = h0.w;
    hA[4] = h1.x; hA[5] = h1.y; hA[6] = h1.z; hA[7] = h1.w;
  }
  {
    const float* hp = hin + (((size_t)mbkB * SEG + sB) << 10) + d * 8;
    const float4 h0 = *(const float4*)&hp[0];
    const float4 h1 = *(const float4*)&hp[4];
    hB[0] = h0.x; hB[1] = h0.y; hB[2] = h0.z; hB[3] = h0.w;
    hB[4] = h1.x; hB[5] = h1.y; hB[6] = h1.z; hB[7] = h1.w;
  }

  float* __restrict__ yd = (p == 0 ? yrow : ycol) + off0;
  const ptrdiff_t sstep = (ptrdiff_t)stepPos * DD;

  float va[32];
  if (fA) chainA_<true>(tA, xr, aln2A, wA, bwA, dsvA, hA, va);
  else    chainA_<false>(tA, xr, aln2A, wA, bwA, dsvA, hA, va);
  if (fB) chainB_<true>(tB, xr, aln2B, wB, bwB, dsvB, hB, va, yd, sstep);
  else    chainB_<false>(tB, xr, aln2B, wB, bwB, dsvB, hB, va, yd, sstep);
}

// ---------------- K6: LN(yrow+ycol) * silu(z) @ out_w^T via MFMA ----------
__global__ __launch_bounds__(256) void k_outproj(
    const float* __restrict__ yrow, const float* __restrict__ ycol,
    const float* __restrict__ xz, const float* __restrict__ ln_g,
    const float* __restrict__ ln_b, const float* __restrict__ out_w,
    float* __restrict__ guided) {
  const int lt = blockIdx.x, mb = blockIdx.y;
  const int m = mb >> 2;
  __shared__ float sv[32][132];
  __shared__ float smr[32][2];
  __shared__ float sg[128], sb[128];
  const int tid = threadIdx.x;
  const size_t yoff = ((size_t)mb * LL + lt * 32) * DD;
  const float4* p0 = (const float4*)(yrow + yoff);
  const float4* p1 = (const float4*)(ycol + yoff);
  float4 ya[4], yb[4];
#pragma unroll
  for (int t = 0; t < 4; ++t) { ya[t] = p0[tid + t * 256]; yb[t] = p1[tid + t * 256]; }
  const int zc = tid >> 1, zh = tid & 1;
  const float4* zsrc = (const float4*)(xz + ((size_t)mb * 256 + 128 + zc) * LL + lt * 32 + zh * 16);
  float4 zv[4];
#pragma unroll
  for (int t = 0; t < 4; ++t) zv[t] = zsrc[t];
  if (tid < 128) { sg[tid] = ln_g[m * DD + tid]; sb[tid] = ln_b[m * DD + tid]; }
#pragma unroll
  for (int t = 0; t < 4; ++t) {
    const int idx = tid + t * 256;
    float4 v;
    v.x = ya[t].x + yb[t].x; v.y = ya[t].y + yb[t].y;
    v.z = ya[t].z + yb[t].z; v.w = ya[t].w + yb[t].w;
    *(float4*)&sv[idx >> 5][(idx & 31) << 2] = v;
  }
  __syncthreads();
  {
    const int l = tid >> 3, q = tid & 7;
    float s = 0.f, s2 = 0.f;
#pragma unroll
    for (int d0 = 0; d0 < 16; d0 += 4) {
      const float4 v = *(const float4*)&sv[l][q * 16 + d0];
      s += v.x + v.y + v.z + v.w;
      s2 += v.x * v.x + v.y * v.y + v.z * v.z + v.w * v.w;
    }
    s = dpp_add_<0xB1>(s); s = dpp_add_<0x4E>(s); s = dpp_add_<0x141>(s);
    s2 = dpp_add_<0xB1>(s2); s2 = dpp_add_<0x4E>(s2); s2 = dpp_add_<0x141>(s2);
    if (q == 0) {
      const float mean = s * (1.f / 128.f);
      smr[l][0] = mean;
      smr[l][1] = rsqrtf(fmaf(s2, 1.f / 128.f, -mean * mean) + 1e-5f);
    }
  }
  __syncthreads();
  {
    const float g = sg[zc], bb = sb[zc];
    const float* zf = (const float*)zv;
#pragma unroll
    for (int i2 = 0; i2 < 16; ++i2) {
      const int l = zh * 16 + i2;
      const float v = fmaf((sv[l][zc] - smr[l][0]) * smr[l][1], g, bb);
      sv[l][zc] = v * silu_(zf[i2]);
    }
  }
  __syncthreads();
  // --- MFMA GEMM: D[c][l] = W[c,:] . sv[l,:] ---
  const int lane = tid & 63, wv = tid >> 6;
  const int l0 = (wv & 1) * 16, c0 = (wv >> 1) * 64;
  const int lr = lane & 15, kg = (lane >> 4) * 8;
  const float* __restrict__ Wm = out_w + (size_t)m * DD * DD;
  f32x4 acc[4] = {};
#pragma unroll
  for (int ks = 0; ks < 4; ++ks) {
    const int d0 = ks * 32 + kg;
    const bf16x8 bfr = cvt8(*(const float4*)&sv[l0 + lr][d0],
                            *(const float4*)&sv[l0 + lr][d0 + 4]);
#pragma unroll
    for (int ctl = 0; ctl < 4; ++ctl) {
      const float* __restrict__ wp = Wm + (size_t)(c0 + ctl * 16 + lr) * DD + d0;
      const bf16x8 afr = cvt8(*(const float4*)wp, *(const float4*)(wp + 4));
      acc[ctl] = __builtin_amdgcn_mfma_f32_16x16x32_bf16(afr, bfr, acc[ctl], 0, 0, 0);
    }
  }
  const int lo = l0 + lr;
  const int cb = c0 + (lane >> 4) * 4;
  float* __restrict__ dst = guided + ((size_t)mb * LL + lt * 32 + lo) * DD;
#pragma unroll
  for (int ctl = 0; ctl < 4; ++ctl) {
    float4 v = make_float4(acc[ctl][0], acc[ctl][1], acc[ctl][2], acc[ctl][3]);
    *(float4*)&dst[cb + ctl * 16] = v;
  }
}

// ---------------- K7: enhance via MFMA (LN->GEMM->bias->GELU->+resid) -----
__global__ __launch_bounds__(256) void k_enhance(
    const float* __restrict__ guided, const float* __restrict__ eg,
    const float* __restrict__ ebv, const float* __restrict__ ew,
    const float* __restrict__ ebias, const float* __restrict__ sar,
    const float* __restrict__ opt, float* __restrict__ outp) {
  const int lt = blockIdx.x, ib = blockIdx.y;
  const int i = ib >> 2, b = ib & 3;
  __shared__ float sv[32][132];
  __shared__ float smr[32][2];
  __shared__ float sg[128], sb2[128], sbias[128];
  const int tid = threadIdx.x;
  const float4* gsrc =
      (const float4*)(guided + (((size_t)(1 - i) * 4 + b) * LL + lt * 32) * DD);
  float4 gv[4];
#pragma unroll
  for (int t = 0; t < 4; ++t) gv[t] = gsrc[tid + t * 256];
  if (tid < 128) {
    sg[tid] = eg[i * DD + tid];
    sb2[tid] = ebv[i * DD + tid];
    sbias[tid] = ebias[i * DD + tid];
  }
#pragma unroll
  for (int t = 0; t < 4; ++t) {
    const int idx = tid + t * 256;
    *(float4*)&sv[idx >> 5][(idx & 31) << 2] = gv[t];
  }
  __syncthreads();
  {
    const int l = tid >> 3, q = tid & 7;
    float s = 0.f, s2 = 0.f;
#pragma unroll
    for (int d0 = 0; d0 < 16; d0 += 4) {
      const float4 v = *(const float4*)&sv[l][q * 16 + d0];
      s += v.x + v.y + v.z + v.w;
      s2 += v.x * v.x + v.y * v.y + v.z * v.z + v.w * v.w;
    }
    s = dpp_add_<0xB1>(s); s = dpp_add_<0x4E>(s); s = dpp_add_<0x141>(s);
    s2 = dpp_add_<0xB1>(s2); s2 = dpp_add_<0x4E>(s2); s2 = dpp_add_<0x141>(s2);
    if (q == 0) {
      const float mean = s * (1.f / 128.f);
      smr[l][0] = mean;
      smr[l][1] = rsqrtf(fmaf(s2, 1.f / 128.f, -mean * mean) + 1e-5f);
    }
  }
  __syncthreads();
  {
    const int c = tid >> 1, half = tid & 1;
    const float g = sg[c], bb = sb2[c];
#pragma unroll
    for (int i2 = 0; i2 < 16; ++i2) {
      const int l = half * 16 + i2;
      sv[l][c] = fmaf((sv[l][c] - smr[l][0]) * smr[l][1], g, bb);
    }
  }
  __syncthreads();
  // --- MFMA GEMM + fused epilogue ---
  const int lane = tid & 63, wv = tid >> 6;
  const int l0 = (wv & 1) * 16, c0 = (wv >> 1) * 64;
  const int lr = lane & 15, kg = (lane >> 4) * 8;
  const float* __restrict__ Wm = ew + (size_t)i * DD * DD;
  f32x4 acc[4] = {};
#pragma unroll
  for (int ks = 0; ks < 4; ++ks) {
    const int d0 = ks * 32 + kg;
    const bf16x8 bfr = cvt8(*(const float4*)&sv[l0 + lr][d0],
                            *(const float4*)&sv[l0 + lr][d0 + 4]);
#pragma unroll
    for (int ctl = 0; ctl < 4; ++ctl) {
      const float* __restrict__ wp = Wm + (size_t)(c0 + ctl * 16 + lr) * DD + d0;
      const bf16x8 afr = cvt8(*(const float4*)wp, *(const float4*)(wp + 4));
      acc[ctl] = __builtin_amdgcn_mfma_f32_16x16x32_bf16(afr, bfr, acc[ctl], 0, 0, 0);
    }
  }
  const int lo = l0 + lr;
  const int cb = c0 + (lane >> 4) * 4;
  const float* __restrict__ resid =
      (i == 0 ? sar : opt) + ((size_t)b * LL + lt * 32 + lo) * DD;
  float* __restrict__ dst =
      outp + (size_t)i * (4 * LL * DD) + ((size_t)b * LL + lt * 32 + lo) * DD;
#pragma unroll
  for (int ctl = 0; ctl < 4; ++ctl) {
    const int c = cb + ctl * 16;
    const float4 bia = *(const float4*)&sbias[c];
    const float4 rr = *(const float4*)&resid[c];
    float4 o;
    o.x = rr.x + gelu_(acc[ctl][0] + bia.x);
    o.y = rr.y + gelu_(acc[ctl][1] + bia.y);
    o.z = rr.z + gelu_(acc[ctl][2] + bia.z);
    o.w = rr.w + gelu_(acc[ctl][3] + bia.w);
    *(float4*)&dst[c] = o;
  }
}

extern "C" void kernel_launch(void* const* d_in, const int* in_sizes, int n_in,
                              void* d_out, int out_size, void* d_ws, size_t ws_size,
                              hipStream_t stream) {
  (void)in_sizes; (void)n_in; (void)out_size; (void)ws_size;
  const float* sar    = (const float*)d_in[0];
  const float* opt    = (const float*)d_in[1];
  const float* in_w   = (const float*)d_in[2];
  const float* conv_w = (const float*)d_in[3];
  const float* conv_b = (const float*)d_in[4];
  const float* xproj_w= (const float*)d_in[5];
  const float* dt_w   = (const float*)d_in[6];
  const float* dt_b   = (const float*)d_in[7];
  const float* Alogs  = (const float*)d_in[8];
  const float* Ds     = (const float*)d_in[9];
  const float* ln_g   = (const float*)d_in[10];
  const float* ln_b   = (const float*)d_in[11];
  const float* out_w  = (const float*)d_in[12];
  const float* eg     = (const float*)d_in[13];
  const float* eb     = (const float*)d_in[14];
  const float* ew     = (const float*)d_in[15];
  const float* ebias  = (const float*)d_in[16];

  float* ws     = (float*)d_ws;
  float* xz     = ws;                  // 8,388,608
  float* xc     = xz + 8388608;        // 4,194,304
  float* xdbl   = xc + 4194304;        // 3,145,728
  float* yrowb  = xdbl + 3145728;      // 4,194,304
  float* ycolb  = yrowb + 4194304;     // 4,194,304
  float* guided = ycolb + 4194304;     // 4,194,304
  float* hend   = guided + 4194304;    // 4,194,304
  float* Pseg   = hend + 4194304;      // 4,194,304
  float* hin    = Pseg + 4194304;      // 4,194,304
  float* outf   = (float*)d_out;

  k_inproj <<<dim3(64, 4, 8), 256, 0, stream>>>(sar, opt, in_w, xz);
  k_conv   <<<dim3(4, 16, 8), 256, 0, stream>>>(xz, conv_w, conv_b, xc);
  k_xproj  <<<dim3(64, 2, 8), 256, 0, stream>>>(xc, xproj_w, xdbl);
  k_scan1  <<<dim3(128, 2, 8), 128, 0, stream>>>(xc, xdbl, dt_w, dt_b, Alogs, hend, Pseg);
  k_scan2  <<<dim3(128), 256, 0, stream>>>(hend, Pseg, hin);
  k_scan3  <<<dim3(128, 2, 8), 128, 0, stream>>>(xc, xdbl, dt_w, dt_b, Alogs, Ds, hin,
                                                 yrowb, ycolb);
  k_outproj<<<dim3(128, 8), 256, 0, stream>>>(yrowb, ycolb, xz, ln_g, ln_b, out_w, guided);
  k_enhance<<<dim3(128, 8), 256, 0, stream>>>(guided, eg, eb, ew, ebias, sar, opt, outf);
}

// Round 18
// 241.910 us; speedup vs baseline: 1.1904x; 1.1904x over previous
//
#include <hip/hip_runtime.h>
#include <hip/hip_bf16.h>
#include <math.h>

#define DEV __device__ __forceinline__

static constexpr int LL = 4096;   // H*W
static constexpr int DD = 128;    // hidden
static constexpr int SEG = 128;   // segments per scan (32 positions each)
static constexpr float LOG2E = 1.4426950408889634f;
static constexpr float LN2 = 0.6931471805599453f;

typedef short bf16x8 __attribute__((ext_vector_type(8)));
typedef float f32x4 __attribute__((ext_vector_type(4)));

DEV float silu_(float x) { return x / (1.f + __expf(-x)); }
// A&S 7.1.26 erf approximation, |err| <= 1.5e-7
DEV float erf_(float x) {
  const float ax = fabsf(x);
  const float t = 1.f / fmaf(0.3275911f, ax, 1.f);
  float p = fmaf(1.061405429f, t, -1.453152027f);
  p = fmaf(p, t, 1.421413741f);
  p = fmaf(p, t, -0.284496736f);
  p = fmaf(p, t, 0.254829592f);
  p = p * t;
  const float r = 1.f - p * __expf(-ax * ax);
  return x < 0.f ? -r : r;
}
DEV float gelu_(float x) { return 0.5f * x * (1.f + erf_(x * 0.7071067811865475f)); }
DEV float sp_(float x) {
  const float t = __builtin_amdgcn_exp2f(-fabsf(x) * LOG2E);
  return fmaxf(x, 0.f) + LN2 * __builtin_amdgcn_logf(1.f + t);
}

template <int CTRL>
DEV float dpp_add_(float x) {
  int y = __builtin_amdgcn_update_dpp(0, __float_as_int(x), CTRL, 0xF, 0xF, true);
  return x + __int_as_float(y);
}

DEV short f2bf(float f) {
  unsigned u = __float_as_uint(f);
  u += 0x7FFF + ((u >> 16) & 1);
  return (short)(u >> 16);
}
DEV bf16x8 cvt8(float4 a, float4 b) {
  bf16x8 r;
  r[0] = f2bf(a.x); r[1] = f2bf(a.y); r[2] = f2bf(a.z); r[3] = f2bf(a.w);
  r[4] = f2bf(b.x); r[5] = f2bf(b.y); r[6] = f2bf(b.z); r[7] = f2bf(b.w);
  return r;
}

// 64-position tiles (used by x_proj): tile s of direction k
DEV void seg_base_step(int k, int s, int& base, int& step) {
  if (k == 0)      { base = s * 64;        step = 1;   }
  else if (k == 1) { base = s;             step = 64;  }
  else if (k == 2) { base = 4095 - s * 64; step = -1;  }
  else             { base = 4095 - s;      step = -64; }
}

// ---------------- K1: in_proj via bf16 MFMA; coalesced store via LDS ------
__global__ __launch_bounds__(256) void k_inproj(
    const float* __restrict__ sar, const float* __restrict__ opt,
    const float* __restrict__ in_w, float* __restrict__ xz) {
  const int lt = blockIdx.x, ct = blockIdx.y, mb = blockIdx.z;
  const int m = mb >> 2;
  const float* __restrict__ x = (m == 0 ? opt : sar) + (size_t)(mb & 3) * (LL * DD);
  const float* __restrict__ W = in_w + (size_t)m * 256 * DD + (size_t)ct * 64 * DD;
  __shared__ float sOut[64][65];
  const int tid = threadIdx.x;
  const int lane = tid & 63, wv = tid >> 6;
  const int lr = lane & 15, kg = (lane >> 4) * 8;
  const int lrow = lt * 64 + wv * 16 + lr;            // x row / output col
  f32x4 acc[4] = {};
#pragma unroll
  for (int ks = 0; ks < 4; ++ks) {
    const int d0 = ks * 32 + kg;
    const float* __restrict__ xp = x + (size_t)lrow * DD + d0;
    const bf16x8 bfr = cvt8(*(const float4*)xp, *(const float4*)(xp + 4));
#pragma unroll
    for (int ctl = 0; ctl < 4; ++ctl) {
      const float* __restrict__ wp = W + (size_t)(ctl * 16 + lr) * DD + d0;
      const bf16x8 afr = cvt8(*(const float4*)wp, *(const float4*)(wp + 4));
      acc[ctl] = __builtin_amdgcn_mfma_f32_16x16x32_bf16(afr, bfr, acc[ctl], 0, 0, 0);
    }
  }
  // stage [c][l] tile in LDS, write rows coalesced
  const int lloc = wv * 16 + lr;
  const int cr0 = (lane >> 4) * 4;
#pragma unroll
  for (int ctl = 0; ctl < 4; ++ctl)
#pragma unroll
    for (int r = 0; r < 4; ++r)
      sOut[cr0 + ctl * 16 + r][lloc] = acc[ctl][r];
  __syncthreads();
  float* __restrict__ dst = xz + (size_t)mb * 256 * LL + lt * 64;
#pragma unroll
  for (int t = 0; t < 4; ++t) {
    const int idx = tid + t * 256;
    const int row = idx >> 4, c4 = (idx & 15) << 2;
    *(float4*)&dst[(size_t)(ct * 64 + row) * LL + c4] = *(const float4*)&sOut[row][c4];
  }
}

// ---------------- K2: depthwise 3x3 SAME conv + bias + SiLU ---------------
__global__ __launch_bounds__(256) void k_conv(
    const float* __restrict__ xz, const float* __restrict__ conv_w,
    const float* __restrict__ conv_b, float* __restrict__ xc) {
  const int ht = blockIdx.x, dg = blockIdx.y, mb = blockIdx.z;
  const int m = mb >> 2;
  __shared__ float sIn[8][18][66];
  __shared__ float sOut[1024][8];
  const float* __restrict__ src = xz + ((size_t)mb * 256 + dg * 8) * LL;
  const int tid = threadIdx.x;
  for (int idx = tid; idx < 8 * 18 * 66; idx += 256) {
    const int dd = idx / (18 * 66);
    const int rem = idx - dd * (18 * 66);
    const int hh = rem / 66, ww = rem - hh * 66;
    const int h = ht * 16 + hh - 1, w = ww - 1;
    float v = 0.f;
    if (h >= 0 && h < 64 && w >= 0 && w < 64) v = src[(size_t)dd * LL + h * 64 + w];
    sIn[dd][hh][ww] = v;
  }
  __syncthreads();
  const int dd = tid & 7, wv = tid >> 3;
  const int dch = dg * 8 + dd;
  float wk[9];
#pragma unroll
  for (int t = 0; t < 9; ++t) wk[t] = conv_w[((size_t)m * DD + dch) * 9 + t];
  const float bias = conv_b[m * DD + dch];
  for (int hh = 0; hh < 16; ++hh) {
#pragma unroll
    for (int wh = 0; wh < 2; ++wh) {
      const int w = wv + wh * 32;
      float s = bias;
#pragma unroll
      for (int kh = 0; kh < 3; ++kh)
#pragma unroll
        for (int kw = 0; kw < 3; ++kw)
          s = fmaf(sIn[dd][hh + kh][w + kw], wk[kh * 3 + kw], s);
      sOut[hh * 64 + w][dd] = silu_(s);
    }
  }
  __syncthreads();
  float* __restrict__ dst = xc + (size_t)mb * LL * DD + dg * 8;
#pragma unroll
  for (int r = 0; r < 4; ++r) {
    const int pos = tid + r * 256;
    const int l = ht * 1024 + pos;
    *(float4*)&dst[(size_t)l * DD + 0] = *(const float4*)&sOut[pos][0];
    *(float4*)&dst[(size_t)l * DD + 4] = *(const float4*)&sOut[pos][4];
  }
}

// ---------------- K3: x_proj (paired dirs k, k+2) -> xdbl[mbk][l][24] -----
__global__ __launch_bounds__(256) void k_xproj(
    const float* __restrict__ xc, const float* __restrict__ xproj_w,
    float* __restrict__ xdbl) {
  const int lt = blockIdx.x, p = blockIdx.y, mb = blockIdx.z;
  const int m = mb >> 2;
  const int mbkA = mb * 4 + p, mbkB = mb * 4 + p + 2;
  __shared__ float sX[64][132];
  __shared__ float sWA[24][132];
  __shared__ float sWB[24][132];
  const int tid = threadIdx.x;
  const float* __restrict__ src = xc + (size_t)mb * LL * DD;
  int base, step;
  seg_base_step(p, lt, base, step);
  for (int idx = tid; idx < 64 * 32; idx += 256) {
    const int l = idx >> 5, d4 = (idx & 31) << 2;
    *(float4*)&sX[l][d4] = *(const float4*)&src[(size_t)(base + l * step) * DD + d4];
  }
  const float* __restrict__ WsA = xproj_w + ((size_t)m * 4 + p) * 24 * DD;
  const float* __restrict__ WsB = xproj_w + ((size_t)m * 4 + p + 2) * 24 * DD;
  for (int idx = tid; idx < 24 * 32; idx += 256) {
    const int r = idx >> 5, d4 = (idx & 31) << 2;
    *(float4*)&sWA[r][d4] = *(const float4*)&WsA[(size_t)r * DD + d4];
    *(float4*)&sWB[r][d4] = *(const float4*)&WsB[(size_t)r * DD + d4];
  }
  __syncthreads();
  const int l = tid >> 2, cg = tid & 3;
  float acc[6] = {}, acc2[6] = {};
#pragma unroll 8
  for (int d = 0; d < 128; d += 4) {
    const float4 xv = *(const float4*)&sX[l][d];
#pragma unroll
    for (int j = 0; j < 6; ++j) {
      const float4 wa = *(const float4*)&sWA[cg * 6 + j][d];
      const float4 wb = *(const float4*)&sWB[cg * 6 + j][d];
      acc[j] += xv.x * wa.x + xv.y * wa.y + xv.z * wa.z + xv.w * wa.w;
      acc2[j] += xv.x * wb.x + xv.y * wb.y + xv.z * wb.z + xv.w * wb.w;
    }
  }
  const int rowA = lt * 64 + l;
  float* __restrict__ dstA = xdbl + ((size_t)mbkA * LL + rowA) * 24 + cg * 6;
  float* __restrict__ dstB = xdbl + ((size_t)mbkB * LL + (4095 - rowA)) * 24 + cg * 6;
#pragma unroll
  for (int j = 0; j < 6; ++j) { dstA[j] = acc[j]; dstB[j] = acc2[j]; }
}

// ============== dual-chain segmented selective scan (SEGL=32) =============
// x strip staged once in LDS (16 KB, shared by both chains); t24 rows read
// from global at wave-uniform addresses (scalar/broadcast, L1-hot).

DEV void load_aln2(const float* __restrict__ Alogs, int m, int k, int d,
                   float* __restrict__ aln2, bool& fastp) {
  const float4 a0 = *(const float4*)&Alogs[((size_t)m * 512 + k * DD + d) * 8];
  const float4 a1 = *(const float4*)&Alogs[((size_t)m * 512 + k * DD + d) * 8 + 4];
  aln2[0] = -__expf(a0.x) * LOG2E; aln2[1] = -__expf(a0.y) * LOG2E;
  aln2[2] = -__expf(a0.z) * LOG2E; aln2[3] = -__expf(a0.w) * LOG2E;
  aln2[4] = -__expf(a1.x) * LOG2E; aln2[5] = -__expf(a1.y) * LOG2E;
  aln2[6] = -__expf(a1.z) * LOG2E; aln2[7] = -__expf(a1.w) * LOG2E;
  fastp = true;
#pragma unroll
  for (int n = 1; n < 8; ++n)
    fastp = fastp && (fabsf(aln2[n] - (float)(n + 1) * aln2[0]) <=
                      1e-4f * fabsf(aln2[n]) + 1e-12f);
}

DEV void load_w8(const float* __restrict__ dt_w, int mbk, int d,
                 float* __restrict__ wreg) {
  const float4 w0 = *(const float4*)&dt_w[((size_t)mbk * DD + d) * 8];
  const float4 w1 = *(const float4*)&dt_w[((size_t)mbk * DD + d) * 8 + 4];
  wreg[0] = w0.x; wreg[1] = w0.y; wreg[2] = w0.z; wreg[3] = w0.w;
  wreg[4] = w1.x; wreg[5] = w1.y; wreg[6] = w1.z; wreg[7] = w1.w;
}

template <bool FAST>
DEV void qpow_(float dt, const float* __restrict__ aln2, float* __restrict__ q) {
  if constexpr (FAST) {
    q[0] = __builtin_amdgcn_exp2f(dt * aln2[0]);
    q[1] = q[0] * q[0]; q[2] = q[1] * q[0]; q[3] = q[1] * q[1];
    q[4] = q[3] * q[0]; q[5] = q[3] * q[1]; q[6] = q[3] * q[2]; q[7] = q[3] * q[3];
  } else {
#pragma unroll
    for (int n = 0; n < 8; ++n) q[n] = __builtin_amdgcn_exp2f(dt * aln2[n]);
  }
}

// t24 = uniform pointer to this step's 24-float row {dts[8], B[8], C[8]}
DEV float dt_of_(const float* __restrict__ t24,
                 const float* __restrict__ w, float bw) {
  const float4 t0 = *(const float4*)&t24[0];
  const float4 t1 = *(const float4*)&t24[4];
  float s = bw;
  s = fmaf(t0.x, w[0], s); s = fmaf(t0.y, w[1], s);
  s = fmaf(t0.z, w[2], s); s = fmaf(t0.w, w[3], s);
  s = fmaf(t1.x, w[4], s); s = fmaf(t1.y, w[5], s);
  s = fmaf(t1.z, w[6], s); s = fmaf(t1.w, w[7], s);
  return sp_(s);
}

template <bool FAST>
DEV void hstep_(const float* __restrict__ t24, float dt, float x,
                const float* __restrict__ aln2, float* __restrict__ h) {
  const float u = dt * x;
  float q[8];
  qpow_<FAST>(dt, aln2, q);
  const float4 b0 = *(const float4*)&t24[8];
  const float4 b1 = *(const float4*)&t24[12];
  h[0] = fmaf(h[0], q[0], u * b0.x);
  h[1] = fmaf(h[1], q[1], u * b0.y);
  h[2] = fmaf(h[2], q[2], u * b0.z);
  h[3] = fmaf(h[3], q[3], u * b0.w);
  h[4] = fmaf(h[4], q[4], u * b1.x);
  h[5] = fmaf(h[5], q[5], u * b1.y);
  h[6] = fmaf(h[6], q[6], u * b1.z);
  h[7] = fmaf(h[7], q[7], u * b1.w);
}

template <bool FAST>
DEV float ystep_(const float* __restrict__ t24, float dt, float x,
                 const float* __restrict__ aln2, float dsv,
                 float* __restrict__ h) {
  const float u = dt * x;
  float q[8];
  qpow_<FAST>(dt, aln2, q);
  const float4 b0 = *(const float4*)&t24[8];
  const float4 b1 = *(const float4*)&t24[12];
  const float4 c0 = *(const float4*)&t24[16];
  const float4 c1 = *(const float4*)&t24[20];
  float y = dsv * x;
  h[0] = fmaf(h[0], q[0], u * b0.x); y = fmaf(h[0], c0.x, y);
  h[1] = fmaf(h[1], q[1], u * b0.y); y = fmaf(h[1], c0.y, y);
  h[2] = fmaf(h[2], q[2], u * b0.z); y = fmaf(h[2], c0.z, y);
  h[3] = fmaf(h[3], q[3], u * b0.w); y = fmaf(h[3], c0.w, y);
  h[4] = fmaf(h[4], q[4], u * b1.x); y = fmaf(h[4], c1.x, y);
  h[5] = fmaf(h[5], q[5], u * b1.y); y = fmaf(h[5], c1.y, y);
  h[6] = fmaf(h[6], q[6], u * b1.z); y = fmaf(h[6], c1.z, y);
  h[7] = fmaf(h[7], q[7], u * b1.w); y = fmaf(h[7], c1.w, y);
  return y;
}

// ---- pass 1: dual-chain local scan (h0=0) -> h_end, P --------------------
template <bool FAST>
DEV void loop1d_(const float* __restrict__ tA, const float* __restrict__ tB,
                 const float* __restrict__ sx, int d,
                 const float* __restrict__ aln2A, const float* __restrict__ aln2B,
                 const float* __restrict__ wA, const float* __restrict__ wB,
                 float bwA, float bwB, float* __restrict__ hA,
                 float* __restrict__ hB, float& dtsA, float& dtsB) {
#pragma unroll 8
  for (int j = 0; j < 32; ++j) {
    const float xA = sx[j * 128 + d];
    const float xB = sx[(31 - j) * 128 + d];
    const float dtA = dt_of_(tA + j * 24, wA, bwA);
    const float dtB = dt_of_(tB + j * 24, wB, bwB);
    dtsA += dtA; dtsB += dtB;
    hstep_<FAST>(tA + j * 24, dtA, xA, aln2A, hA);
    hstep_<FAST>(tB + j * 24, dtB, xB, aln2B, hB);
  }
}

__global__ __launch_bounds__(128) void k_scan1(
    const float* __restrict__ xc, const float* __restrict__ xdbl,
    const float* __restrict__ dt_w, const float* __restrict__ dt_b,
    const float* __restrict__ Alogs, float* __restrict__ hend,
    float* __restrict__ Pseg) {
  const int s = blockIdx.x, p = blockIdx.y, mb = blockIdx.z;
  const int m = mb >> 2;
  const int kA = p, kB = p + 2;
  const int sA = s, sB = 127 - s;
  const int mbkA = mb * 4 + kA, mbkB = mb * 4 + kB;
  const int d = threadIdx.x;
  __shared__ float sx[32 * 128];   // 16 KB

  const float* __restrict__ tA = xdbl + ((size_t)mbkA * LL + sA * 32) * 24;
  const float* __restrict__ tB = xdbl + ((size_t)mbkB * LL + sB * 32) * 24;

  const int base0 = (p == 0) ? s * 32 : ((s & 1) * 32) * 64 + (s >> 1);
  const int stepPos = (p == 0) ? 1 : 64;
  const float* __restrict__ xsrc = xc + (size_t)mb * LL * DD;
#pragma unroll
  for (int t = 0; t < 8; ++t) {
    const int idx = d + t * 128;
    const int r = idx >> 5, c4 = (idx & 31) << 2;
    ((float4*)sx)[idx] = *(const float4*)&xsrc[(size_t)(base0 + r * stepPos) * DD + c4];
  }

  float aln2A[8], aln2B[8]; bool fA, fB;
  load_aln2(Alogs, m, kA, d, aln2A, fA);
  load_aln2(Alogs, m, kB, d, aln2B, fB);
  float wA[8], wB[8];
  load_w8(dt_w, mbkA, d, wA);
  load_w8(dt_w, mbkB, d, wB);
  const float bwA = dt_b[(size_t)mbkA * DD + d];
  const float bwB = dt_b[(size_t)mbkB * DD + d];
  __syncthreads();

  float hA[8] = {0, 0, 0, 0, 0, 0, 0, 0};
  float hB[8] = {0, 0, 0, 0, 0, 0, 0, 0};
  float dtsA = 0.f, dtsB = 0.f;
  if (fA && fB)
    loop1d_<true>(tA, tB, sx, d, aln2A, aln2B, wA, wB, bwA, bwB, hA, hB, dtsA, dtsB);
  else
    loop1d_<false>(tA, tB, sx, d, aln2A, aln2B, wA, wB, bwA, bwB, hA, hB, dtsA, dtsB);

  {
    float* __restrict__ he = hend + (((size_t)mbkA * SEG + sA) << 10) + d * 8;
    float* __restrict__ pe = Pseg + (((size_t)mbkA * SEG + sA) << 10) + d * 8;
    *(float4*)&he[0] = make_float4(hA[0], hA[1], hA[2], hA[3]);
    *(float4*)&he[4] = make_float4(hA[4], hA[5], hA[6], hA[7]);
    *(float4*)&pe[0] = make_float4(
        __builtin_amdgcn_exp2f(aln2A[0] * dtsA), __builtin_amdgcn_exp2f(aln2A[1] * dtsA),
        __builtin_amdgcn_exp2f(aln2A[2] * dtsA), __builtin_amdgcn_exp2f(aln2A[3] * dtsA));
    *(float4*)&pe[4] = make_float4(
        __builtin_amdgcn_exp2f(aln2A[4] * dtsA), __builtin_amdgcn_exp2f(aln2A[5] * dtsA),
        __builtin_amdgcn_exp2f(aln2A[6] * dtsA), __builtin_amdgcn_exp2f(aln2A[7] * dtsA));
  }
  {
    float* __restrict__ he = hend + (((size_t)mbkB * SEG + sB) << 10) + d * 8;
    float* __restrict__ pe = Pseg + (((size_t)mbkB * SEG + sB) << 10) + d * 8;
    *(float4*)&he[0] = make_float4(hB[0], hB[1], hB[2], hB[3]);
    *(float4*)&he[4] = make_float4(hB[4], hB[5], hB[6], hB[7]);
    *(float4*)&pe[0] = make_float4(
        __builtin_amdgcn_exp2f(aln2B[0] * dtsB), __builtin_amdgcn_exp2f(aln2B[1] * dtsB),
        __builtin_amdgcn_exp2f(aln2B[2] * dtsB), __builtin_amdgcn_exp2f(aln2B[3] * dtsB));
    *(float4*)&pe[4] = make_float4(
        __builtin_amdgcn_exp2f(aln2B[4] * dtsB), __builtin_amdgcn_exp2f(aln2B[5] * dtsB),
        __builtin_amdgcn_exp2f(aln2B[6] * dtsB), __builtin_amdgcn_exp2f(aln2B[7] * dtsB));
  }
}

// ---- pass 2: sequential combine across 128 segments -> h_in --------------
__global__ __launch_bounds__(256) void k_scan2(
    const float* __restrict__ hend, const float* __restrict__ Pseg,
    float* __restrict__ hin) {
  const int gid = blockIdx.x * 256 + threadIdx.x;   // 32768
  const int mbk = gid >> 10, dn = gid & 1023;
  const float* __restrict__ P = Pseg + ((size_t)mbk * SEG << 10) + dn;
  const float* __restrict__ E = hend + ((size_t)mbk * SEG << 10) + dn;
  float* __restrict__ O = hin + ((size_t)mbk * SEG << 10) + dn;
  float h = 0.f;
  for (int c0 = 0; c0 < SEG; c0 += 16) {
    float pv[16], ev[16];
#pragma unroll
    for (int t = 0; t < 16; ++t) {
      pv[t] = P[(size_t)(c0 + t) << 10];
      ev[t] = E[(size_t)(c0 + t) << 10];
    }
#pragma unroll
    for (int t = 0; t < 16; ++t) {
      O[(size_t)(c0 + t) << 10] = h;
      h = fmaf(pv[t], h, ev[t]);
    }
  }
}

// ---- pass 3: dual-chain seeded scan; chains combined in registers --------
template <bool FAST>
DEV void chainA_(const float* __restrict__ t24, const float* __restrict__ sx, int d,
                 const float* __restrict__ aln2, const float* __restrict__ w,
                 float bw, float dsv, float* __restrict__ h,
                 float* __restrict__ va) {
#pragma unroll
  for (int j = 0; j < 32; ++j) {
    const float x = sx[j * 128 + d];
    const float dt = dt_of_(t24 + j * 24, w, bw);
    va[j] = ystep_<FAST>(t24 + j * 24, dt, x, aln2, dsv, h);
  }
}

template <bool FAST>
DEV void chainB_(const float* __restrict__ t24, const float* __restrict__ sx, int d,
                 const float* __restrict__ aln2, const float* __restrict__ w,
                 float bw, float dsv, float* __restrict__ h,
                 const float* __restrict__ va, float* __restrict__ yd,
                 ptrdiff_t sstep) {
#pragma unroll
  for (int j = 0; j < 32; ++j) {
    const int phys = 31 - j;
    const float x = sx[phys * 128 + d];
    const float dt = dt_of_(t24 + j * 24, w, bw);
    const float v = ystep_<FAST>(t24 + j * 24, dt, x, aln2, dsv, h);
    yd[(ptrdiff_t)phys * sstep] = v + va[phys];
  }
}

__global__ __launch_bounds__(128) void k_scan3(
    const float* __restrict__ xc, const float* __restrict__ xdbl,
    const float* __restrict__ dt_w, const float* __restrict__ dt_b,
    const float* __restrict__ Alogs, const float* __restrict__ Ds,
    const float* __restrict__ hin, float* __restrict__ yrow,
    float* __restrict__ ycol) {
  const int s = blockIdx.x, p = blockIdx.y, mb = blockIdx.z;
  const int m = mb >> 2;
  const int kA = p, kB = p + 2;
  const int sA = s, sB = 127 - s;
  const int mbkA = mb * 4 + kA, mbkB = mb * 4 + kB;
  const int d = threadIdx.x;
  __shared__ float sx[32 * 128];   // 16 KB

  const float* __restrict__ tA = xdbl + ((size_t)mbkA * LL + sA * 32) * 24;
  const float* __restrict__ tB = xdbl + ((size_t)mbkB * LL + sB * 32) * 24;

  const int base0 = (p == 0) ? s * 32 : ((s & 1) * 32) * 64 + (s >> 1);
  const int stepPos = (p == 0) ? 1 : 64;
  const float* __restrict__ xsrc = xc + (size_t)mb * LL * DD;
#pragma unroll
  for (int t = 0; t < 8; ++t) {
    const int idx = d + t * 128;
    const int r = idx >> 5, c4 = (idx & 31) << 2;
    ((float4*)sx)[idx] = *(const float4*)&xsrc[(size_t)(base0 + r * stepPos) * DD + c4];
  }

  float aln2A[8], aln2B[8]; bool fA, fB;
  load_aln2(Alogs, m, kA, d, aln2A, fA);
  load_aln2(Alogs, m, kB, d, aln2B, fB);
  float wA[8], wB[8];
  load_w8(dt_w, mbkA, d, wA);
  load_w8(dt_w, mbkB, d, wB);
  const float bwA = dt_b[(size_t)mbkA * DD + d];
  const float bwB = dt_b[(size_t)mbkB * DD + d];
  const float dsvA = Ds[(size_t)m * 512 + kA * DD + d];
  const float dsvB = Ds[(size_t)m * 512 + kB * DD + d];

  float hA[8], hB[8];
  {
    const float* hp = hin + (((size_t)mbkA * SEG + sA) << 10) + d * 8;
    const float4 h0 = *(const float4*)&hp[0];
    const float4 h1 = *(const float4*)&hp[4];
    hA[0] = h0.x; hA[1] = h0.y; hA[2] = h0.z; hA[3] = h0.w;
    hA[4] = h1.x; hA[5] = h1.y; hA[6] = h1.z; hA[7] = h1.w;
  }
  {
    const float* hp = hin + (((size_t)mbkB * SEG + sB) << 10) + d * 8;
    const float4 h0 = *(const float4*)&hp[0];
    const float4 h1 = *(const float4*)&hp[4];
    hB[0] = h0.x; hB[1] = h0.y; hB[2] = h0.z; hB[3] = h0.w;
    hB[4] = h1.x; hB[5] = h1.y; hB[6] = h1.z; hB[7] = h1.w;
  }

  const size_t off0 = (size_t)mb * LL * DD + (size_t)base0 * DD + d;
  float* __restrict__ yd = (p == 0 ? yrow : ycol) + off0;
  const ptrdiff_t sstep = (ptrdiff_t)stepPos * DD;
  __syncthreads();

  float va[32];
  if (fA) chainA_<true>(tA, sx, d, aln2A, wA, bwA, dsvA, hA, va);
  else    chainA_<false>(tA, sx, d, aln2A, wA, bwA, dsvA, hA, va);
  if (fB) chainB_<true>(tB, sx, d, aln2B, wB, bwB, dsvB, hB, va, yd, sstep);
  else    chainB_<false>(tB, sx, d, aln2B, wB, bwB, dsvB, hB, va, yd, sstep);
}

// ---------------- K6: LN(yrow+ycol) * silu(z) @ out_w^T via MFMA ----------
__global__ __launch_bounds__(256) void k_outproj(
    const float* __restrict__ yrow, const float* __restrict__ ycol,
    const float* __restrict__ xz, const float* __restrict__ ln_g,
    const float* __restrict__ ln_b, const float* __restrict__ out_w,
    float* __restrict__ guided) {
  const int lt = blockIdx.x, mb = blockIdx.y;
  const int m = mb >> 2;
  __shared__ float sv[32][132];
  __shared__ float smr[32][2];
  __shared__ float sg[128], sb[128];
  const int tid = threadIdx.x;
  const size_t yoff = ((size_t)mb * LL + lt * 32) * DD;
  const float4* p0 = (const float4*)(yrow + yoff);
  const float4* p1 = (const float4*)(ycol + yoff);
  float4 ya[4], yb[4];
#pragma unroll
  for (int t = 0; t < 4; ++t) { ya[t] = p0[tid + t * 256]; yb[t] = p1[tid + t * 256]; }
  const int zc = tid >> 1, zh = tid & 1;
  const float4* zsrc = (const float4*)(xz + ((size_t)mb * 256 + 128 + zc) * LL + lt * 32 + zh * 16);
  float4 zv[4];
#pragma unroll
  for (int t = 0; t < 4; ++t) zv[t] = zsrc[t];
  if (tid < 128) { sg[tid] = ln_g[m * DD + tid]; sb[tid] = ln_b[m * DD + tid]; }
#pragma unroll
  for (int t = 0; t < 4; ++t) {
    const int idx = tid + t * 256;
    float4 v;
    v.x = ya[t].x + yb[t].x; v.y = ya[t].y + yb[t].y;
    v.z = ya[t].z + yb[t].z; v.w = ya[t].w + yb[t].w;
    *(float4*)&sv[idx >> 5][(idx & 31) << 2] = v;
  }
  __syncthreads();
  {
    const int l = tid >> 3, q = tid & 7;
    float s = 0.f, s2 = 0.f;
#pragma unroll
    for (int d0 = 0; d0 < 16; d0 += 4) {
      const float4 v = *(const float4*)&sv[l][q * 16 + d0];
      s += v.x + v.y + v.z + v.w;
      s2 += v.x * v.x + v.y * v.y + v.z * v.z + v.w * v.w;
    }
    s = dpp_add_<0xB1>(s); s = dpp_add_<0x4E>(s); s = dpp_add_<0x141>(s);
    s2 = dpp_add_<0xB1>(s2); s2 = dpp_add_<0x4E>(s2); s2 = dpp_add_<0x141>(s2);
    if (q == 0) {
      const float mean = s * (1.f / 128.f);
      smr[l][0] = mean;
      smr[l][1] = rsqrtf(fmaf(s2, 1.f / 128.f, -mean * mean) + 1e-5f);
    }
  }
  __syncthreads();
  {
    const float g = sg[zc], bb = sb[zc];
    const float* zf = (const float*)zv;
#pragma unroll
    for (int i2 = 0; i2 < 16; ++i2) {
      const int l = zh * 16 + i2;
      const float v = fmaf((sv[l][zc] - smr[l][0]) * smr[l][1], g, bb);
      sv[l][zc] = v * silu_(zf[i2]);
    }
  }
  __syncthreads();
  // --- MFMA GEMM: D[c][l] = W[c,:] . sv[l,:] ---
  const int lane = tid & 63, wv = tid >> 6;
  const int l0 = (wv & 1) * 16, c0 = (wv >> 1) * 64;
  const int lr = lane & 15, kg = (lane >> 4) * 8;
  const float* __restrict__ Wm = out_w + (size_t)m * DD * DD;
  f32x4 acc[4] = {};
#pragma unroll
  for (int ks = 0; ks < 4; ++ks) {
    const int d0 = ks * 32 + kg;
    const bf16x8 bfr = cvt8(*(const float4*)&sv[l0 + lr][d0],
                            *(const float4*)&sv[l0 + lr][d0 + 4]);
#pragma unroll
    for (int ctl = 0; ctl < 4; ++ctl) {
      const float* __restrict__ wp = Wm + (size_t)(c0 + ctl * 16 + lr) * DD + d0;
      const bf16x8 afr = cvt8(*(const float4*)wp, *(const float4*)(wp + 4));
      acc[ctl] = __builtin_amdgcn_mfma_f32_16x16x32_bf16(afr, bfr, acc[ctl], 0, 0, 0);
    }
  }
  const int lo = l0 + lr;
  const int cb = c0 + (lane >> 4) * 4;
  float* __restrict__ dst = guided + ((size_t)mb * LL + lt * 32 + lo) * DD;
#pragma unroll
  for (int ctl = 0; ctl < 4; ++ctl) {
    float4 v = make_float4(acc[ctl][0], acc[ctl][1], acc[ctl][2], acc[ctl][3]);
    *(float4*)&dst[cb + ctl * 16] = v;
  }
}

// ---------------- K7: enhance via MFMA (LN->GEMM->bias->GELU->+resid) -----
__global__ __launch_bounds__(256) void k_enhance(
    const float* __restrict__ guided, const float* __restrict__ eg,
    const float* __restrict__ ebv, const float* __restrict__ ew,
    const float* __restrict__ ebias, const float* __restrict__ sar,
    const float* __restrict__ opt, float* __restrict__ outp) {
  const int lt = blockIdx.x, ib = blockIdx.y;
  const int i = ib >> 2, b = ib & 3;
  __shared__ float sv[32][132];
  __shared__ float smr[32][2];
  __shared__ float sg[128], sb2[128], sbias[128];
  const int tid = threadIdx.x;
  const float4* gsrc =
      (const float4*)(guided + (((size_t)(1 - i) * 4 + b) * LL + lt * 32) * DD);
  float4 gv[4];
#pragma unroll
  for (int t = 0; t < 4; ++t) gv[t] = gsrc[tid + t * 256];
  if (tid < 128) {
    sg[tid] = eg[i * DD + tid];
    sb2[tid] = ebv[i * DD + tid];
    sbias[tid] = ebias[i * DD + tid];
  }
#pragma unroll
  for (int t = 0; t < 4; ++t) {
    const int idx = tid + t * 256;
    *(float4*)&sv[idx >> 5][(idx & 31) << 2] = gv[t];
  }
  __syncthreads();
  {
    const int l = tid >> 3, q = tid & 7;
    float s = 0.f, s2 = 0.f;
#pragma unroll
    for (int d0 = 0; d0 < 16; d0 += 4) {
      const float4 v = *(const float4*)&sv[l][q * 16 + d0];
      s += v.x + v.y + v.z + v.w;
      s2 += v.x * v.x + v.y * v.y + v.z * v.z + v.w * v.w;
    }
    s = dpp_add_<0xB1>(s); s = dpp_add_<0x4E>(s); s = dpp_add_<0x141>(s);
    s2 = dpp_add_<0xB1>(s2); s2 = dpp_add_<0x4E>(s2); s2 = dpp_add_<0x141>(s2);
    if (q == 0) {
      const float mean = s * (1.f / 128.f);
      smr[l][0] = mean;
      smr[l][1] = rsqrtf(fmaf(s2, 1.f / 128.f, -mean * mean) + 1e-5f);
    }
  }
  __syncthreads();
  {
    const int c = tid >> 1, half = tid & 1;
    const float g = sg[c], bb = sb2[c];
#pragma unroll
    for (int i2 = 0; i2 < 16; ++i2) {
      const int l = half * 16 + i2;
      sv[l][c] = fmaf((sv[l][c] - smr[l][0]) * smr[l][1], g, bb);
    }
  }
  __syncthreads();
  // --- MFMA GEMM + fused epilogue ---
  const int lane = tid & 63, wv = tid >> 6;
  const int l0 = (wv & 1) * 16, c0 = (wv >> 1) * 64;
  const int lr = lane & 15, kg = (lane >> 4) * 8;
  const float* __restrict__ Wm = ew + (size_t)i * DD * DD;
  f32x4 acc[4] = {};
#pragma unroll
  for (int ks = 0; ks < 4; ++ks) {
    const int d0 = ks * 32 + kg;
    const bf16x8 bfr = cvt8(*(const float4*)&sv[l0 + lr][d0],
                            *(const float4*)&sv[l0 + lr][d0 + 4]);
#pragma unroll
    for (int ctl = 0; ctl < 4; ++ctl) {
      const float* __restrict__ wp = Wm + (size_t)(c0 + ctl * 16 + lr) * DD + d0;
      const bf16x8 afr = cvt8(*(const float4*)wp, *(const float4*)(wp + 4));
      acc[ctl] = __builtin_amdgcn_mfma_f32_16x16x32_bf16(afr, bfr, acc[ctl], 0, 0, 0);
    }
  }
  const int lo = l0 + lr;
  const int cb = c0 + (lane >> 4) * 4;
  const float* __restrict__ resid =
      (i == 0 ? sar : opt) + ((size_t)b * LL + lt * 32 + lo) * DD;
  float* __restrict__ dst =
      outp + (size_t)i * (4 * LL * DD) + ((size_t)b * LL + lt * 32 + lo) * DD;
#pragma unroll
  for (int ctl = 0; ctl < 4; ++ctl) {
    const int c = cb + ctl * 16;
    const float4 bia = *(const float4*)&sbias[c];
    const float4 rr = *(const float4*)&resid[c];
    float4 o;
    o.x = rr.x + gelu_(acc[ctl][0] + bia.x);
    o.y = rr.y + gelu_(acc[ctl][1] + bia.y);
    o.z = rr.z + gelu_(acc[ctl][2] + bia.z);
    o.w = rr.w + gelu_(acc[ctl][3] + bia.w);
    *(float4*)&dst[c] = o;
  }
}

extern "C" void kernel_launch(void* const* d_in, const int* in_sizes, int n_in,
                              void* d_out, int out_size, void* d_ws, size_t ws_size,
                              hipStream_t stream) {
  (void)in_sizes; (void)n_in; (void)out_size; (void)ws_size;
  const float* sar    = (const float*)d_in[0];
  const float* opt    = (const float*)d_in[1];
  const float* in_w   = (const float*)d_in[2];
  const float* conv_w = (const float*)d_in[3];
  const float* conv_b = (const float*)d_in[4];
  const float* xproj_w= (const float*)d_in[5];
  const float* dt_w   = (const float*)d_in[6];
  const float* dt_b   = (const float*)d_in[7];
  const float* Alogs  = (const float*)d_in[8];
  const float* Ds     = (const float*)d_in[9];
  const float* ln_g   = (const float*)d_in[10];
  const float* ln_b   = (const float*)d_in[11];
  const float* out_w  = (const float*)d_in[12];
  const float* eg     = (const float*)d_in[13];
  const float* eb     = (const float*)d_in[14];
  const float* ew     = (const float*)d_in[15];
  const float* ebias  = (const float*)d_in[16];

  float* ws     = (float*)d_ws;
  float* xz     = ws;                  // 8,388,608
  float* xc     = xz + 8388608;        // 4,194,304
  float* xdbl   = xc + 4194304;        // 3,145,728
  float* yrowb  = xdbl + 3145728;      // 4,194,304
  float* ycolb  = yrowb + 4194304;     // 4,194,304
  float* guided = ycolb + 4194304;     // 4,194,304
  float* hend   = guided + 4194304;    // 4,194,304
  float* Pseg   = hend + 4194304;      // 4,194,304
  float* hin    = Pseg + 4194304;      // 4,194,304
  float* outf   = (float*)d_out;

  k_inproj <<<dim3(64, 4, 8), 256, 0, stream>>>(sar, opt, in_w, xz);
  k_conv   <<<dim3(4, 16, 8), 256, 0, stream>>>(xz, conv_w, conv_b, xc);
  k_xproj  <<<dim3(64, 2, 8), 256, 0, stream>>>(xc, xproj_w, xdbl);
  k_scan1  <<<dim3(128, 2, 8), 128, 0, stream>>>(xc, xdbl, dt_w, dt_b, Alogs, hend, Pseg);
  k_scan2  <<<dim3(128), 256, 0, stream>>>(hend, Pseg, hin);
  k_scan3  <<<dim3(128, 2, 8), 128, 0, stream>>>(xc, xdbl, dt_w, dt_b, Alogs, Ds, hin,
                                                 yrowb, ycolb);
  k_outproj<<<dim3(128, 8), 256, 0, stream>>>(yrowb, ycolb, xz, ln_g, ln_b, out_w, guided);
  k_enhance<<<dim3(128, 8), 256, 0, stream>>>(guided, eg, eb, ew, ebias, sar, opt, outf);
}